// Round 6
// baseline (593.369 us; speedup 1.0000x reference)
//
#include <hip/hip_runtime.h>
#include <math.h>

#define BATCH 2
#define TSTEPS 8

typedef __attribute__((ext_vector_type(8))) short s16x8;   // 8 bf16 (4 VGPRs)
typedef __attribute__((ext_vector_type(4))) float f32x4;   // MFMA accum

__device__ __forceinline__ float hsig(float v){ return fminf(fmaxf(0.2f*v+0.5f,0.f),1.f); }

__device__ __forceinline__ ushort f2bf(float f){
    uint u = __builtin_bit_cast(uint, f);
    u = (u + 0x7FFFu + ((u >> 16) & 1u)) >> 16;   // round-to-nearest-even
    return (ushort)u;
}

__global__ void cast_bf16_kernel(const float* __restrict__ src, ushort* __restrict__ dst, int n){
    int i = blockIdx.x * 256 + threadIdx.x;
    if (i < n) dst[i] = f2bf(src[i]);
}

// W [K][N] fp32 -> Wt [N'][K] bf16, gate-interleaved: dest row n' = co*4+g <- src col g*Co+co.
__global__ void transw_kernel(const float* __restrict__ W, ushort* __restrict__ Wt,
                              int K, int N, int Co){
    int i = blockIdx.x * 256 + threadIdx.x;
    if (i >= K * N) return;
    int n = i / K, k = i - n * K;
    int g = n & 3, co = n >> 2;
    Wt[i] = f2bf(W[(size_t)k * N + g * Co + co]);
}

// ---------------------------------------------------------------------------
// convx: implicit-im2col GEMM, bf16 MFMA, NO LDS / NO barriers.
// Each wave owns a 64x64 tile (4x4 MFMA 16x16x32); wg = 2x2 waves = 128x128.
// A and B fragments loaded directly global->VGPR (16 B per lane, contiguous).
// Zx out fp32 [M][N'] gate-interleaved (n' = co*4+g), bias added.
// ---------------------------------------------------------------------------
template<int CI, int CO>
__global__ __launch_bounds__(256) void convx_mfma(
    const ushort* __restrict__ Abf, const ushort* __restrict__ Wt,
    const float* __restrict__ bias, float* __restrict__ Zx,
    int H, int Wd)
{
    constexpr int K = 9 * CI;
    constexpr int N = 4 * CO;

    const int tid = threadIdx.x;
    const int m0 = blockIdx.x * 128, n0 = blockIdx.y * 128;
    const int lane = tid & 63, wave = tid >> 6;
    const int wm = wave >> 1, wn = wave & 1;
    const int quad = lane >> 4, l16 = lane & 15;
    const int HW = H * Wd;

    // per-mt pixel coords (lane-variant): row = m0 + wm*64 + mt*16 + l16
    int py[4], px[4], pbt[4];
    #pragma unroll
    for (int mt = 0; mt < 4; ++mt){
        const int p = m0 + wm * 64 + mt * 16 + l16;
        pbt[mt] = p / HW;
        const int rem = p - pbt[mt] * HW;
        py[mt] = rem / Wd; px[mt] = rem - (rem / Wd) * Wd;
    }
    // B row pointers
    const ushort* bp[4];
    #pragma unroll
    for (int nt = 0; nt < 4; ++nt)
        bp[nt] = &Wt[(size_t)(n0 + wn * 64 + nt * 16 + l16) * K + quad * 8];

    f32x4 acc[4][4] = {};

    #pragma unroll
    for (int tap = 0; tap < 9; ++tap){
        const int kh = tap / 3, kw = tap - (tap / 3) * 3;
        const ushort* ap[4]; bool va[4];
        #pragma unroll
        for (int mt = 0; mt < 4; ++mt){
            const int yy = py[mt] + kh - 1, xx = px[mt] + kw - 1;
            va[mt] = (yy >= 0 && yy < H && xx >= 0 && xx < Wd);
            ap[mt] = &Abf[((size_t)(pbt[mt] * H + (va[mt] ? yy : 0)) * Wd + (va[mt] ? xx : 0)) * CI + quad * 8];
        }
        #pragma unroll
        for (int ci0 = 0; ci0 < CI; ci0 += 32){
            s16x8 af[4], bf[4];
            #pragma unroll
            for (int mt = 0; mt < 4; ++mt){
                s16x8 v = *(const s16x8*)(ap[mt] + ci0);
                af[mt] = va[mt] ? v : (s16x8)0;
            }
            #pragma unroll
            for (int nt = 0; nt < 4; ++nt)
                bf[nt] = *(const s16x8*)(bp[nt] + tap * CI + ci0);
            #pragma unroll
            for (int mt = 0; mt < 4; ++mt)
                #pragma unroll
                for (int nt = 0; nt < 4; ++nt)
                    acc[mt][nt] = __builtin_amdgcn_mfma_f32_16x16x32_bf16(af[mt], bf[nt], acc[mt][nt], 0, 0, 0);
        }
    }

    #pragma unroll
    for (int mt = 0; mt < 4; ++mt){
        #pragma unroll
        for (int nt = 0; nt < 4; ++nt){
            const int col = n0 + wn * 64 + nt * 16 + l16;      // interleaved col co*4+g
            const float bv = bias[(col & 3) * CO + (col >> 2)];
            #pragma unroll
            for (int r = 0; r < 4; ++r){
                const int row = m0 + wm * 64 + mt * 16 + quad * 4 + r;
                Zx[(size_t)row * N + col] = acc[mt][nt][r] + bv;
            }
        }
    }
}

// ---------------------------------------------------------------------------
// LSTM step: z = Zx[t] + conv(h_prev, Wh), bf16 MFMA, no-LDS K-loop.
// Wave tile 32x32 (2x2 MFMA); wg = 2x2 waves = 64x64.
// Epilogue: per-wave LDS stash of z, one barrier, gates+BN+2x2 upsample.
// ---------------------------------------------------------------------------
template<int CO, int OUT_BF16>
__global__ __launch_bounds__(256) void step_mfma(
    const float* __restrict__ Zx, const ushort* __restrict__ Wht,
    const ushort* __restrict__ hprev, ushort* __restrict__ hnew,
    float* __restrict__ cst,
    const float* __restrict__ gamma, const float* __restrict__ beta,
    const float* __restrict__ mmean, const float* __restrict__ mvar,
    void* __restrict__ outp, int H, int Wd, int t)
{
    constexpr int K = 9 * CO;
    constexpr int N4 = 4 * CO;

    __shared__ float Zs[4][32][36];   // per-wave z stash (18.4 KB)

    const int tid = threadIdx.x;
    const int m0 = blockIdx.x * 64, n0 = blockIdx.y * 64;
    const int lane = tid & 63, wave = tid >> 6;
    const int wm = wave >> 1, wn = wave & 1;
    const int quad = lane >> 4, l16 = lane & 15;
    const int HW = H * Wd;

    int py[2], px[2], pb[2];
    #pragma unroll
    for (int mt = 0; mt < 2; ++mt){
        const int p = m0 + wm * 32 + mt * 16 + l16;
        pb[mt] = p / HW;
        const int rem = p - pb[mt] * HW;
        py[mt] = rem / Wd; px[mt] = rem - (rem / Wd) * Wd;
    }
    const ushort* bp[2];
    #pragma unroll
    for (int nt = 0; nt < 2; ++nt)
        bp[nt] = &Wht[(size_t)(n0 + wn * 32 + nt * 16 + l16) * K + quad * 8];

    f32x4 acc[2][2] = {};

    #pragma unroll
    for (int tap = 0; tap < 9; ++tap){
        const int kh = tap / 3, kw = tap - (tap / 3) * 3;
        const ushort* ap[2]; bool va[2];
        #pragma unroll
        for (int mt = 0; mt < 2; ++mt){
            const int yy = py[mt] + kh - 1, xx = px[mt] + kw - 1;
            va[mt] = (yy >= 0 && yy < H && xx >= 0 && xx < Wd);
            ap[mt] = &hprev[((size_t)(pb[mt] * H + (va[mt] ? yy : 0)) * Wd + (va[mt] ? xx : 0)) * CO + quad * 8];
        }
        #pragma unroll
        for (int ci0 = 0; ci0 < CO; ci0 += 32){
            s16x8 af[2], bf[2];
            #pragma unroll
            for (int mt = 0; mt < 2; ++mt){
                s16x8 v = *(const s16x8*)(ap[mt] + ci0);
                af[mt] = va[mt] ? v : (s16x8)0;
            }
            #pragma unroll
            for (int nt = 0; nt < 2; ++nt)
                bf[nt] = *(const s16x8*)(bp[nt] + tap * CO + ci0);
            #pragma unroll
            for (int mt = 0; mt < 2; ++mt)
                #pragma unroll
                for (int nt = 0; nt < 2; ++nt)
                    acc[mt][nt] = __builtin_amdgcn_mfma_f32_16x16x32_bf16(af[mt], bf[nt], acc[mt][nt], 0, 0, 0);
        }
    }

    // stash z into per-wave LDS region: Zs[wave][pixel 0..31][ncol 0..31]
    #pragma unroll
    for (int mt = 0; mt < 2; ++mt)
        #pragma unroll
        for (int nt = 0; nt < 2; ++nt)
            #pragma unroll
            for (int r = 0; r < 4; ++r)
                Zs[wave][mt * 16 + quad * 4 + r][nt * 16 + l16] = acc[mt][nt][r];
    __syncthreads();

    // epilogue: 64 pixels x 16 co per wg; 1024 pairs over 256 threads x 4
    const int co0 = n0 >> 2;
    #pragma unroll
    for (int it = 0; it < 4; ++it){
        const int idx = it * 256 + tid;
        const int pp = idx >> 4, lco = idx & 15;
        const int wave2 = (pp >> 5) * 2 + (lco >> 3);
        const float4 zs = *(const float4*)&Zs[wave2][pp & 31][(lco & 7) * 4];

        const int m = m0 + pp;
        const int b2 = m / HW; const int rr = m - b2 * HW;
        const int y2 = rr / Wd, x2 = rr - (rr / Wd) * Wd;
        const int co = co0 + lco;

        const size_t zrow = (size_t)(b2 * TSTEPS + t) * HW + rr;
        const float4 zx = *(const float4*)&Zx[zrow * N4 + co * 4];

        const float iv = hsig(zs.x + zx.x), fv = hsig(zs.y + zx.y);
        const float gv = tanhf(zs.z + zx.z), ov = hsig(zs.w + zx.w);
        const float cold = cst[(size_t)m * CO + co];
        const float cn = fv * cold + iv * gv;
        cst[(size_t)m * CO + co] = cn;
        const float h = ov * tanhf(cn);
        hnew[(size_t)m * CO + co] = f2bf(h);

        const float bnv = (h - mmean[co]) * rsqrtf(mvar[co] + 1e-3f) * gamma[co] + beta[co];
        const int W2 = 2 * Wd;
        const size_t ob = ((size_t)(b2 * TSTEPS + t) * 2 * H + 2 * y2) * W2 + 2 * x2;
        if (OUT_BF16){
            ushort* o = (ushort*)outp; const ushort hv = f2bf(bnv);
            o[ob * CO + co] = hv; o[(ob + 1) * CO + co] = hv;
            o[(ob + W2) * CO + co] = hv; o[(ob + W2 + 1) * CO + co] = hv;
        } else {
            float* o = (float*)outp;
            o[ob * CO + co] = bnv; o[(ob + 1) * CO + co] = bnv;
            o[(ob + W2) * CO + co] = bnv; o[(ob + W2 + 1) * CO + co] = bnv;
        }
    }
}

template<int CI, int CO, int OUT_BF16>
static void run_block(const ushort* xbf, const ushort* Wxt, const ushort* Wht, const float* bias,
                      const float* g, const float* be, const float* mm, const float* mv,
                      float* Zx, ushort* hA, ushort* hB, float* cbuf, void* out,
                      int H, int W, hipStream_t stream)
{
    const int M = BATCH * TSTEPS * H * W;
    dim3 gx(M / 128, (4 * CO) / 128);
    convx_mfma<CI, CO><<<gx, 256, 0, stream>>>(xbf, Wxt, bias, Zx, H, W);

    hipMemsetAsync(hA, 0, (size_t)BATCH * H * W * CO * sizeof(ushort), stream);
    hipMemsetAsync(cbuf, 0, (size_t)BATCH * H * W * CO * sizeof(float), stream);

    const int Ms = BATCH * H * W;
    dim3 gs(Ms / 64, (4 * CO) / 64);
    for (int t = 0; t < TSTEPS; ++t){
        const ushort* hp = (t & 1) ? hB : hA;
        ushort* hn = (t & 1) ? hA : hB;
        step_mfma<CO, OUT_BF16><<<gs, 256, 0, stream>>>(Zx, Wht, hp, hn, cbuf, g, be, mm, mv, out, H, W, t);
    }
}

extern "C" void kernel_launch(void* const* d_in, const int* in_sizes, int n_in,
                              void* d_out, int out_size, void* d_ws, size_t ws_size,
                              hipStream_t stream) {
    const float* x   = (const float*)d_in[0];
    const float* Wx1 = (const float*)d_in[1];  const float* Wh1 = (const float*)d_in[2];
    const float* b1  = (const float*)d_in[3];  const float* g1  = (const float*)d_in[4];
    const float* be1 = (const float*)d_in[5];  const float* mm1 = (const float*)d_in[6];
    const float* mv1 = (const float*)d_in[7];
    const float* Wx2 = (const float*)d_in[8];  const float* Wh2 = (const float*)d_in[9];
    const float* b2  = (const float*)d_in[10]; const float* g2  = (const float*)d_in[11];
    const float* be2 = (const float*)d_in[12]; const float* mm2 = (const float*)d_in[13];
    const float* mv2 = (const float*)d_in[14];
    const float* Wx3 = (const float*)d_in[15]; const float* Wh3 = (const float*)d_in[16];
    const float* b3  = (const float*)d_in[17]; const float* g3  = (const float*)d_in[18];
    const float* be3 = (const float*)d_in[19]; const float* mm3 = (const float*)d_in[20];
    const float* mv3 = (const float*)d_in[21];

    char* ws = (char*)d_ws;
    size_t off = 0;
    auto alloc = [&](size_t bytes) { char* p = ws + off; off += (bytes + 255) & ~(size_t)255; return p; };

    float*  Zx   = (float*)alloc(8388608ull * 4);      // max Zx (block3: 65536*128)
    float*  cbuf = (float*)alloc(262144ull * 4);       // max c (block3: 8192*32)
    ushort* xbf  = (ushort*)alloc(786432ull * 2);      // x cast
    ushort* x2   = (ushort*)alloc(2097152ull * 2);     // block1 out (bf16)
    ushort* x3   = (ushort*)alloc(4194304ull * 2);     // block2 out (bf16)
    ushort* hA   = (ushort*)alloc(262144ull * 2);
    ushort* hB   = (ushort*)alloc(262144ull * 2);
    ushort* Wxt1 = (ushort*)alloc(884736ull * 2);
    ushort* Wxt2 = (ushort*)alloc(294912ull * 2);
    ushort* Wxt3 = (ushort*)alloc(73728ull * 2);
    ushort* Wht1 = (ushort*)alloc(589824ull * 2);
    ushort* Wht2 = (ushort*)alloc(147456ull * 2);
    ushort* Wht3 = (ushort*)alloc(36864ull * 2);

    // prep: casts + gate-interleaved weight transposes (both Wx and Wh)
    cast_bf16_kernel<<<(786432 + 255) / 256, 256, 0, stream>>>(x, xbf, 786432);
    transw_kernel<<<(884736 + 255) / 256, 256, 0, stream>>>(Wx1, Wxt1, 1728, 512, 128);
    transw_kernel<<<(294912 + 255) / 256, 256, 0, stream>>>(Wx2, Wxt2, 1152, 256, 64);
    transw_kernel<<<(73728  + 255) / 256, 256, 0, stream>>>(Wx3, Wxt3,  576, 128, 32);
    transw_kernel<<<(589824 + 255) / 256, 256, 0, stream>>>(Wh1, Wht1, 1152, 512, 128);
    transw_kernel<<<(147456 + 255) / 256, 256, 0, stream>>>(Wh2, Wht2,  576, 256, 64);
    transw_kernel<<<(36864  + 255) / 256, 256, 0, stream>>>(Wh3, Wht3,  288, 128, 32);

    run_block<192, 128, 1>(xbf, Wxt1, Wht1, b1, g1, be1, mm1, mv1, Zx, hA, hB, cbuf, x2, 16, 16, stream);
    run_block<128,  64, 1>(x2,  Wxt2, Wht2, b2, g2, be2, mm2, mv2, Zx, hA, hB, cbuf, x3, 32, 32, stream);
    run_block< 64,  32, 0>(x3,  Wxt3, Wht3, b3, g3, be3, mm3, mv3, Zx, hA, hB, cbuf, d_out, 64, 64, stream);
}